// Round 1
// baseline (559.470 us; speedup 1.0000x reference)
//
#include <hip/hip_runtime.h>
#include <cstdint>
#include <cstddef>

#define D_NUM 4
#define N_ES  2
#define N_SH  4
#define DIN   512
#define HDIM  256
#define BB    16384
#define NMAT  12        // 8 spec (n*2+e) + 4 shared
#define NGATE 36        // 4*6 domain gates + 12 shared gates

typedef __bf16 bf16x8 __attribute__((ext_vector_type(8)));
typedef float  f32x4  __attribute__((ext_vector_type(4)));

__device__ __forceinline__ unsigned short f2bf(float f) {
    union { float f; unsigned u; } v; v.f = f;
    unsigned u = v.u;
    unsigned r = (u + 0x7FFFu + ((u >> 16) & 1u)) >> 16;   // RNE
    return (unsigned short)r;
}

__device__ __forceinline__ void async16(void* l, const void* g) {
    __builtin_amdgcn_global_load_lds(
        (const __attribute__((address_space(1))) void*)g,
        (__attribute__((address_space(3))) void*)l,
        16, 0, 0);
}

template <int N>
__device__ __forceinline__ void softmaxN(float* z) {
    float m = z[0];
    #pragma unroll
    for (int i = 1; i < N; ++i) m = fmaxf(m, z[i]);
    float s = 0.f;
    #pragma unroll
    for (int i = 0; i < N; ++i) { z[i] = __expf(z[i] - m); s += z[i]; }
    float r = 1.f / s;
    #pragma unroll
    for (int i = 0; i < N; ++i) z[i] *= r;
}

// ---------------------------------------------------------------------------
// Kernel W: convert + transpose weights to bf16 WT[mat][h][k], mat = n*2+e | 8+e
// ---------------------------------------------------------------------------
__global__ __launch_bounds__(256) void k_wconv(
    const float* __restrict__ Wspec,   // (4,2,512,256)
    const float* __restrict__ Wsh,     // (4,512,256)
    unsigned short* __restrict__ WT)   // (12,256,512)
{
    int i = blockIdx.x * 256 + threadIdx.x;       // 12*256*512 = 1,572,864 total
    int mat = i >> 17;                            // / (256*512)
    int rem = i & 131071;
    int h = rem >> 9;
    int k = rem & 511;
    float v;
    if (mat < 8) v = Wspec[((size_t)mat * DIN + k) * HDIM + h];
    else         v = Wsh[((size_t)(mat - 8) * DIN + k) * HDIM + h];
    WT[i] = f2bf(v);
}

// ---------------------------------------------------------------------------
// Kernel A: x f32 -> bf16 copy, plus gate probabilities (double softmax + mask)
// One wave per row.
// ---------------------------------------------------------------------------
__global__ __launch_bounds__(256) void k_prep(
    const float* __restrict__ x,        // (5,B,512)
    const int*   __restrict__ simdom,   // (4,2)
    const float* __restrict__ Wg,       // (4,512,6)
    const float* __restrict__ bg,       // (4,6)
    const float* __restrict__ Wgs,      // (512,12)
    const float* __restrict__ bgs,      // (12)
    unsigned short* __restrict__ xbf,   // (5,B,512)
    float* __restrict__ gates)          // (B,36)
{
    const int wave = threadIdx.x >> 6;
    const int lane = threadIdx.x & 63;
    const int row  = blockIdx.x * 4 + wave;
    const int k0   = lane * 8;

    float xv[5][8];
    #pragma unroll
    for (int m = 0; m < 5; ++m) {
        const float4* p = (const float4*)(x + ((size_t)m * BB + row) * DIN + k0);
        float4 a = p[0], b = p[1];
        xv[m][0]=a.x; xv[m][1]=a.y; xv[m][2]=a.z; xv[m][3]=a.w;
        xv[m][4]=b.x; xv[m][5]=b.y; xv[m][6]=b.z; xv[m][7]=b.w;
        union { unsigned short us[8]; uint4 v; } pk;
        #pragma unroll
        for (int j = 0; j < 8; ++j) pk.us[j] = f2bf(xv[m][j]);
        *(uint4*)(xbf + ((size_t)m * BB + row) * DIN + k0) = pk.v;
    }

    float acc[NGATE];
    #pragma unroll
    for (int i = 0; i < NGATE; ++i) acc[i] = 0.f;

    #pragma unroll
    for (int n = 0; n < 4; ++n)
        #pragma unroll
        for (int j = 0; j < 8; ++j) {
            float xk = xv[n][j];
            const float* w = Wg + ((size_t)n * DIN + k0 + j) * 6;
            #pragma unroll
            for (int e = 0; e < 6; ++e) acc[n*6+e] += xk * w[e];
        }
    #pragma unroll
    for (int j = 0; j < 8; ++j) {
        float xk = xv[4][j];
        const float* w = Wgs + (size_t)(k0 + j) * 12;
        #pragma unroll
        for (int e = 0; e < 12; ++e) acc[24+e] += xk * w[e];
    }

    // 64-lane butterfly reduction; result broadcast to all lanes
    #pragma unroll
    for (int off = 32; off > 0; off >>= 1)
        #pragma unroll
        for (int i = 0; i < NGATE; ++i) acc[i] += __shfl_xor(acc[i], off, 64);

    float g[NGATE];
    #pragma unroll
    for (int n = 0; n < 4; ++n) {
        float z[6];
        #pragma unroll
        for (int e = 0; e < 6; ++e) z[e] = acc[n*6+e] + bg[n*6+e];
        softmaxN<6>(z);                               // first softmax
        int s0 = simdom[n*2], s1 = simdom[n*2+1];
        float z2[6];
        z2[0] = z[0]; z2[1] = z[1];
        #pragma unroll
        for (int j = 0; j < 4; ++j)
            z2[2+j] = (s0 == j || s1 == j) ? z[2+j] : -1e30f;
        softmaxN<6>(z2);                              // masked second softmax
        #pragma unroll
        for (int e = 0; e < 6; ++e) g[n*6+e] = z2[e];
    }
    {
        float z[12];
        #pragma unroll
        for (int e = 0; e < 12; ++e) z[e] = acc[24+e] + bgs[e];
        softmaxN<12>(z);
        #pragma unroll
        for (int e = 0; e < 12; ++e) g[24+e] = z[e];
    }
    if (lane < NGATE) gates[(size_t)row * NGATE + lane] = g[lane];
}

// ---------------------------------------------------------------------------
// Kernel B: fused 12-matrix GEMM + bias + ReLU + gate combine.
// Block tile 64 rows x 32 h-cols; 4 waves in 2x2; BK=32; 16 K-steps.
// LDS x tiles [5][64][32], W tiles [12][32][32], 16B k-chunks XOR-swizzled by
// (row>>1)&3 (swizzle applied on the *global* source lane so global_load_lds's
// forced lane-ordered LDS layout stays valid; reads land 2-way = free).
// ---------------------------------------------------------------------------
__global__ __launch_bounds__(256, 2) void k_main(
    const unsigned short* __restrict__ xbf,   // (5,B,512)
    const unsigned short* __restrict__ WT,    // (12,256,512)
    const float* __restrict__ gates,          // (B,36)
    const float* __restrict__ bspec,          // (4,2,256)
    const float* __restrict__ bsh,            // (4,256)
    float* __restrict__ out)                  // (5,B,256)
{
    __shared__ unsigned short lx[5 * 64 * 32];    // 20 KB, tile m at m*2048
    __shared__ unsigned short lw[12 * 32 * 32];   // 24 KB, tile mat at mat*1024
    __shared__ float lg[64 * NGATE];              //  9 KB

    const int tid  = threadIdx.x;
    const int wave = tid >> 6;
    const int lane = tid & 63;
    const int row0 = blockIdx.x * 64;
    const int h0   = blockIdx.y * 32;

    // --- staging slots: 44 total (20 x-quarters + 24 W-halves), 11 per wave.
    const unsigned short* gsrc[11];
    unsigned short*       ldst[11];
    #pragma unroll
    for (int i = 0; i < 11; ++i) {
        int s = wave * 11 + i;
        if (s < 20) {
            int m = s >> 2, q = s & 3;
            int r  = q * 16 + (lane >> 2);               // row in 64-row tile
            int cg = (lane & 3) ^ ((r >> 1) & 3);        // swizzled global k-chunk
            gsrc[i] = xbf + ((size_t)m * BB + row0 + r) * DIN + cg * 8;
            ldst[i] = lx + m * 2048 + q * 512;           // wave-uniform LDS base
        } else {
            int s2 = s - 20;
            int mat = s2 >> 1, half = s2 & 1;
            int r  = half * 16 + (lane >> 2);            // h-row in 32-row tile
            int cg = (lane & 3) ^ ((r >> 1) & 3);
            gsrc[i] = WT + (size_t)mat * (HDIM * DIN) + (size_t)(h0 + r) * DIN + cg * 8;
            ldst[i] = lw + mat * 1024 + half * 512;
        }
    }

    f32x4 acc[NMAT][2];
    #pragma unroll
    for (int mat = 0; mat < NMAT; ++mat)
        #pragma unroll
        for (int mp = 0; mp < 2; ++mp)
            acc[mat][mp] = (f32x4){0.f, 0.f, 0.f, 0.f};

    const int wm = wave >> 1, wn = wave & 1;
    const int mrow0 = wm * 32;
    const int col   = wn * 16 + (lane & 15);   // B-frag n (h within tile)
    const int arow  = lane & 15;               // A-frag m (row within 16)
    const int quad  = lane >> 4;               // k-chunk index for frags

    // hoisted LDS read offsets
    int aofs[5][2];
    #pragma unroll
    for (int m = 0; m < 5; ++m)
        #pragma unroll
        for (int mp = 0; mp < 2; ++mp) {
            int r = mrow0 + mp * 16 + arow;
            int c = quad ^ ((r >> 1) & 3);
            aofs[m][mp] = m * 2048 + r * 32 + c * 8;
        }
    int bofs[NMAT];
    #pragma unroll
    for (int mat = 0; mat < NMAT; ++mat) {
        int c = quad ^ ((col >> 1) & 3);
        bofs[mat] = mat * 1024 + col * 32 + c * 8;
    }

    for (int ks = 0; ks < 16; ++ks) {
        __syncthreads();                       // previous tile fully consumed
        #pragma unroll
        for (int i = 0; i < 11; ++i) {
            async16(ldst[i], gsrc[i]);
            gsrc[i] += 32;                     // advance K by 32 elements (64B)
        }
        __syncthreads();                       // staging drained (vmcnt(0) at barrier)

        bf16x8 af[5][2];
        #pragma unroll
        for (int m = 0; m < 5; ++m)
            #pragma unroll
            for (int mp = 0; mp < 2; ++mp)
                af[m][mp] = *(const bf16x8*)(lx + aofs[m][mp]);

        #pragma unroll
        for (int mat = 0; mat < NMAT; ++mat) {
            bf16x8 bf = *(const bf16x8*)(lw + bofs[mat]);
            int ms = (mat < 8) ? (mat >> 1) : 4;
            acc[mat][0] = __builtin_amdgcn_mfma_f32_16x16x32_bf16(af[ms][0], bf, acc[mat][0], 0, 0, 0);
            acc[mat][1] = __builtin_amdgcn_mfma_f32_16x16x32_bf16(af[ms][1], bf, acc[mat][1], 0, 0, 0);
        }
    }

    // --- epilogue: gates to LDS, bias+ReLU, combine, store -----------------
    for (int i = tid; i < 64 * NGATE; i += 256)
        lg[i] = gates[(size_t)(row0 + i / NGATE) * NGATE + (i % NGATE)];
    __syncthreads();

    const int h = h0 + col;
    float bias[NMAT];
    #pragma unroll
    for (int mat = 0; mat < 8; ++mat) bias[mat] = bspec[mat * HDIM + h];
    #pragma unroll
    for (int e = 0; e < 4; ++e)       bias[8+e] = bsh[e * HDIM + h];

    #pragma unroll
    for (int mp = 0; mp < 2; ++mp) {
        #pragma unroll
        for (int reg = 0; reg < 4; ++reg) {
            int rl = mrow0 + mp * 16 + quad * 4 + reg;   // C/D: row=(lane>>4)*4+reg
            float s[NMAT];
            #pragma unroll
            for (int mat = 0; mat < NMAT; ++mat)
                s[mat] = fmaxf(acc[mat][mp][reg] + bias[mat], 0.f);
            const float* g = lg + rl * NGATE;
            float o4 = 0.f;
            #pragma unroll
            for (int j = 0; j < 8; ++j) o4 += g[24 + j] * s[j];
            #pragma unroll
            for (int e = 0; e < 4; ++e) o4 += g[32 + e] * s[8 + e];
            size_t rowg = (size_t)(row0 + rl);
            #pragma unroll
            for (int n = 0; n < 4; ++n) {
                const float* gn = g + n * 6;
                float on = gn[0]*s[n*2] + gn[1]*s[n*2+1]
                         + gn[2]*s[8] + gn[3]*s[9] + gn[4]*s[10] + gn[5]*s[11];
                out[((size_t)n * BB + rowg) * HDIM + h] = on;
            }
            out[((size_t)4 * BB + rowg) * HDIM + h] = o4;
        }
    }
}

// ---------------------------------------------------------------------------
extern "C" void kernel_launch(void* const* d_in, const int* in_sizes, int n_in,
                              void* d_out, int out_size, void* d_ws, size_t ws_size,
                              hipStream_t stream) {
    const float* x      = (const float*)d_in[0];
    const int*   simdom = (const int*)  d_in[1];
    const float* Wspec  = (const float*)d_in[2];
    const float* bspec  = (const float*)d_in[3];
    const float* Wsh    = (const float*)d_in[4];
    const float* bsh    = (const float*)d_in[5];
    const float* Wg     = (const float*)d_in[6];
    const float* bg     = (const float*)d_in[7];
    const float* Wgs    = (const float*)d_in[8];
    const float* bgs    = (const float*)d_in[9];
    float* out = (float*)d_out;

    uint8_t* ws = (uint8_t*)d_ws;
    unsigned short* xbf = (unsigned short*)ws;                       // 83,886,080 B
    unsigned short* WT  = (unsigned short*)(ws + 83886080ull);       //  3,145,728 B
    float*          gts = (float*)(ws + 83886080ull + 3145728ull);   //  2,359,296 B

    k_wconv<<<6144, 256, 0, stream>>>(Wspec, Wsh, WT);
    k_prep<<<BB / 4, 256, 0, stream>>>(x, simdom, Wg, bg, Wgs, bgs, xbf, gts);
    k_main<<<dim3(BB / 64, HDIM / 32), 256, 0, stream>>>(xbf, WT, gts, bspec, bsh, out);
}